// Round 11
// baseline (435.674 us; speedup 1.0000x reference)
//
#include <hip/hip_runtime.h>
#include <math.h>

// Problem constants (fixed by the reference)
#define NHEADS 8
#define HDIM   128
#define WIN    16
#define DIM    1024
#define QKVDIM 3072
#define SEQ    2048
#define BATCH  4
#define MROWS  (BATCH * SEQ)   // 8192
#define RMS_EPS 1e-6f
#define PLANE  ((size_t)MROWS * HDIM)   // one head-plane of q/k/v (8192 x 128)

typedef __bf16 bf16x8 __attribute__((ext_vector_type(8)));
typedef unsigned short u16x8 __attribute__((ext_vector_type(8)));
typedef float  f32x4  __attribute__((ext_vector_type(4)));

// ---------------- bf16 bit helpers (RNE) ----------------
__device__ __forceinline__ unsigned short f2b(float f) {
    union { float f; unsigned u; } c; c.f = f;
    return (unsigned short)((c.u + 0x7FFFu + ((c.u >> 16) & 1u)) >> 16);
}
__device__ __forceinline__ float b2f(unsigned short u) {
    union { unsigned u; float f; } c; c.u = ((unsigned)u) << 16; return c.f;
}
__device__ __forceinline__ bf16x8 u2b(u16x8 u) {
    union { u16x8 u; bf16x8 b; } c; c.u = u; return c.b;
}

// ---------------- fused cast: x + 4 weights + zero sumsq ----------------
__global__ __launch_bounds__(256) void cast_all(const float* __restrict__ x,
                                                const float* __restrict__ w0,
                                                const float* __restrict__ w1,
                                                const float* __restrict__ w2,
                                                const float* __restrict__ w3,
                                                unsigned short* __restrict__ xb,
                                                unsigned short* __restrict__ wb,
                                                float* __restrict__ sumsq)
{
    const int b = blockIdx.x;
    const int t = threadIdx.x;
    if (b >= 12288) {   // zero the 8192x2 f32 sumsq buffer (ws is poisoned 0xAA)
        ((float4*)sumsq)[(b - 12288) * 256 + t] = make_float4(0.f, 0.f, 0.f, 0.f);
        return;
    }
    const float* src;
    unsigned short* dst;
    int i;
    if (b < 8192) {
        i = b * 256 + t;
        src = x; dst = xb;
    } else {
        const int bb = b - 8192;
        const int which = bb >> 10;
        i = (bb & 1023) * 256 + t;
        src = which == 0 ? w0 : which == 1 ? w1 : which == 2 ? w2 : w3;
        dst = wb + (size_t)which * DIM * DIM;
    }
    const float4 v = ((const float4*)src)[i];
    ushort4 o;
    o.x = f2b(v.x); o.y = f2b(v.y); o.z = f2b(v.z); o.w = f2b(v.w);
    ((ushort4*)dst)[i] = o;
}

// ---------------- 128x128 4-wave MFMA GEMM (NT), m97 structure: single-buffer + max TLP ----------------
// BM=BN=128 BK=64, 256 threads = 4 waves (2M x 2N), per-wave 64x64 (acc[4][4]).
// SINGLE-buffered LDS (32 KiB) -> 5 blocks/CU (20 waves/CU). The per-block
// barrier drain (s_waitcnt vmcnt(0) before s_barrier, compiler-emitted) is
// masked by the OTHER resident blocks' waves (guide m97/m114: this cross-block
// TLP is what delivers 874-912 TF; in-kernel pipelining attempts r1/r5/r8 all
// failed to replicate it, and the 2-blocks/CU double-buffer (r10) kept MfmaUtil
// flat at 27%). No setprio (m190: slightly negative on this structure).
// Per K-tile: __syncthreads; stage A(4)+B(4); __syncthreads; frag reads + 32 MFMA.
#define LDA8() { \
    _Pragma("unroll") for (int il = 0; il < 4; ++il) { \
        const int rr = (wm * 64 + il * 16 + frow) * 64; \
        af[il][0] = *(const bf16x8*)&As[rr + cs0]; \
        af[il][1] = *(const bf16x8*)&As[rr + cs1]; \
    } }

#define LDB4(bh, bgr) { \
    _Pragma("unroll") for (int jl = 0; jl < 2; ++jl) { \
        const int rr = (wn * 64 + (bh) * 32 + jl * 16 + frow) * 64; \
        bgr[jl][0] = *(const bf16x8*)&Bs[rr + cs0]; \
        bgr[jl][1] = *(const bf16x8*)&Bs[rr + cs1]; \
    } }

#define MMA16(bh, bgr) { \
    _Pragma("unroll") for (int il = 0; il < 4; ++il) \
    _Pragma("unroll") for (int jl = 0; jl < 2; ++jl) { \
        acc[il][(bh)*2+jl] = __builtin_amdgcn_mfma_f32_16x16x32_bf16(af[il][0], bgr[jl][0], acc[il][(bh)*2+jl], 0, 0, 0); \
        acc[il][(bh)*2+jl] = __builtin_amdgcn_mfma_f32_16x16x32_bf16(af[il][1], bgr[jl][1], acc[il][(bh)*2+jl], 0, 0, 0); \
    } }

// 128 rows / (4 waves x 8 rows per instr) = 4 gload_lds per thread per matrix.
#define STAGE_A(kt) { \
    _Pragma("unroll") for (int s2 = 0; s2 < 4; ++s2) { \
        const int rb = s2 * 32; \
        __builtin_amdgcn_global_load_lds( \
            (const __attribute__((address_space(1))) void*)(gA + (size_t)rb * K + (kt)), \
            (__attribute__((address_space(3))) void*)&As[(rb + wid * 8) * 64], 16, 0, 0); \
    } }

#define STAGE_B(kt) { \
    _Pragma("unroll") for (int s2 = 0; s2 < 4; ++s2) { \
        const int rb = s2 * 32; \
        __builtin_amdgcn_global_load_lds( \
            (const __attribute__((address_space(1))) void*)(gB + (size_t)rb * K + (kt)), \
            (__attribute__((address_space(3))) void*)&Bs[(rb + wid * 8) * 64], 16, 0, 0); \
    } }

template <typename TC, bool PLANAR>
__global__ __launch_bounds__(256, 5) void gemm_nt_128(const unsigned short* __restrict__ A,
                                                      const unsigned short* __restrict__ B,
                                                      TC* __restrict__ C,
                                                      float* __restrict__ sumsq,
                                                      int M, int N, int K)
{
    __shared__ __align__(16) __bf16 As[128 * 64];
    __shared__ __align__(16) __bf16 Bs[128 * 64];

    const int t    = threadIdx.x;
    const int wid  = t >> 6;
    const int lane = t & 63;
    const int wm   = wid >> 1;          // 0..1  (64-row band)
    const int wn   = wid & 1;           // 0..1  (64-col band)
    const int bm0  = blockIdx.y * 128;
    const int bn0  = blockIdx.x * 128;

    const int frow = lane & 15;
    const int quad = lane >> 4;
    const int cs0  = ((quad    ) ^ (frow & 7)) * 8;
    const int cs1  = ((quad + 4) ^ (frow & 7)) * 8;

    const int lr = lane >> 3;
    const int lc = (lane & 7) ^ lr;
    const unsigned short* gA = A + (size_t)(bm0 + wid * 8 + lr) * K + lc * 8;
    const unsigned short* gB = B + (size_t)(bn0 + wid * 8 + lr) * K + lc * 8;

    f32x4 acc[4][4];
    #pragma unroll
    for (int i = 0; i < 4; ++i)
        #pragma unroll
        for (int j = 0; j < 4; ++j)
            #pragma unroll
            for (int e = 0; e < 4; ++e) acc[i][j][e] = 0.f;

    bf16x8 af[4][2], bg0[2][2], bg1[2][2];

    for (int kt = 0; kt < K; kt += 64) {
        __syncthreads();                 // previous tile's ds_reads retired
        STAGE_A(kt); STAGE_B(kt);        // 8 global_load_lds
        __syncthreads();                 // compiler drains vmcnt(0) before barrier;
                                         // the stall is masked by 4 other resident blocks
        LDA8(); LDB4(0, bg0); LDB4(1, bg1);
        MMA16(0, bg0); MMA16(1, bg1);
    }

    // ---- epilogue: C/D layout col=lane&15, row=(lane>>4)*4+reg
    const int m_base = bm0 + wm * 64;
    const int n_base = bn0 + wn * 64;
    if constexpr (PLANAR) {
        // col n -> plane n>>7 (q heads 0-7 | k 8-15 | v 16-23), offset n&127
        size_t cb[4];
        #pragma unroll
        for (int j = 0; j < 4; ++j) {
            const int nb = n_base + j * 16;
            cb[j] = (size_t)(nb >> 7) * PLANE + (nb & 127);
        }
        #pragma unroll
        for (int il = 0; il < 4; ++il)
            #pragma unroll
            for (int r = 0; r < 4; ++r) {
                const size_t row = m_base + il * 16 + quad * 4 + r;
                #pragma unroll
                for (int j = 0; j < 4; ++j)
                    ((unsigned short*)C)[cb[j] + row * HDIM + frow] = f2b(acc[il][j][r]);
            }
        if (sumsq != nullptr && bn0 < 2 * DIM) {
            const int which = bn0 >> 10;   // 0 = q cols, 1 = k cols
            #pragma unroll
            for (int il = 0; il < 4; ++il)
                #pragma unroll
                for (int r = 0; r < 4; ++r) {
                    float p = acc[il][0][r] * acc[il][0][r] + acc[il][1][r] * acc[il][1][r]
                            + acc[il][2][r] * acc[il][2][r] + acc[il][3][r] * acc[il][3][r];
                    p += __shfl_xor(p, 1, 64);
                    p += __shfl_xor(p, 2, 64);
                    p += __shfl_xor(p, 4, 64);
                    p += __shfl_xor(p, 8, 64);
                    if (frow == 0)
                        atomicAdd(&sumsq[(size_t)(m_base + il * 16 + quad * 4 + r) * 2 + which], p);
                }
        }
    } else {
        #pragma unroll
        for (int il = 0; il < 4; ++il)
            #pragma unroll
            for (int r = 0; r < 4; ++r) {
                TC* crow = C + (size_t)(m_base + il * 16 + quad * 4 + r) * N + n_base + frow;
                #pragma unroll
                for (int j = 0; j < 4; ++j)
                    crow[j * 16] = acc[il][j][r];
            }
    }
}

// ---------------- MFMA sliding-window attention (head-planar, K LDS-staged) ----------------
// BYTE-IDENTICAL to rounds 9/10 (best measured attn: qw*kw folded into K
// staging, Q prefetched to regs, per-row rsqrt post-MFMA).
__global__ __launch_bounds__(256) void attn_mfma(const unsigned short* __restrict__ qkvp,
                                                 const float* __restrict__ sumsq,
                                                 const float* __restrict__ qw,
                                                 const float* __restrict__ kw,
                                                 unsigned short* __restrict__ o)
{
    __shared__ __align__(16) unsigned short Klds[80 * 136];
    __shared__ __align__(16) unsigned short Vt[128 * 88];
    __shared__ __align__(16) unsigned short Plds[4 * 16 * 40];

    const int t  = threadIdx.x;
    const int qb = blockIdx.x;
    const int h  = blockIdx.y;
    const int r0 = qb * 64;             // first query's global row
    const int i0 = r0 & (SEQ - 1);      // seq-local (block never spans batches)
    const int bb = r0 - i0;             // batch base row

    const unsigned short* qg = qkvp + (size_t)h * PLANE;
    const unsigned short* kg = qkvp + (size_t)(NHEADS + h) * PLANE;
    const unsigned short* vg = qkvp + (size_t)(2 * NHEADS + h) * PLANE;

    const int w    = t >> 6;
    const int lane = t & 63;
    const int frow = lane & 15;
    const int quad = lane >> 4;
    const int fk   = quad * 8;

    // ---- Q prefetch (raw; latency hidden under staging below)
    const size_t qrow = (size_t)(r0 + w * 16 + frow) * HDIM;
    u16x8 qa[4];
    #pragma unroll
    for (int kt = 0; kt < 4; ++kt)
        qa[kt] = *(const u16x8*)(qg + qrow + kt * 32 + fk);

    // ---- stage K (qw*kw fused) and V (transposed)
    #pragma unroll
    for (int it = 0; it < 5; ++it) {
        const int c = it * 256 + t;
        {   // K rows i0-16 .. i0+63  ->  Klds[0..79][.], scaled by qw*kw per channel
            const int lr2 = c >> 4, c8 = c & 15;
            const int ks = i0 - 16 + lr2;
            const int rc = ks < 0 ? 0 : ks;      // clamped rows masked later
            const u16x8 kv = *(const u16x8*)(kg + (size_t)(bb + rc) * HDIM + c8 * 8);
            u16x8 ko;
            #pragma unroll
            for (int e = 0; e < 8; ++e) {
                const int d = h * HDIM + c8 * 8 + e;
                ko[e] = f2b(b2f(kv[e]) * qw[d] * kw[d]);
            }
            *(u16x8*)&Klds[lr2 * 136 + c8 * 8] = ko;
        }
        {   // V transposed scatter
            const int c8 = c / 80, lr2 = c - c8 * 80;
            const int ks = i0 - 16 + lr2;
            const int rc = ks < 0 ? 0 : ks;      // clamped rows get P == 0
            const u16x8 vv = *(const u16x8*)(vg + (size_t)(bb + rc) * HDIM + c8 * 8);
            #pragma unroll
            for (int e = 0; e < 8; ++e)
                Vt[(c8 * 8 + e) * 88 + lr2] = vv[e];
        }
    }
    __syncthreads();

    // ---- S = Q K^T (Q raw from regs; channel weights already in K)
    const int kidx0 = i0 - 16 + w * 16 + frow;             // s0 key (seq-local)
    const int kr0   = kidx0 < 0 ? 0 : kidx0;               // clamped; masked below

    f32x4 s0 = {0.f, 0.f, 0.f, 0.f}, s1 = {0.f, 0.f, 0.f, 0.f};
    #pragma unroll
    for (int kt = 0; kt < 4; ++kt) {
        const bf16x8 af = u2b(qa[kt]);
        const bf16x8 b0 = *(const bf16x8*)&Klds[(w * 16 + frow) * 136 + kt * 32 + fk];
        const bf16x8 b1 = *(const bf16x8*)&Klds[(w * 16 + 16 + frow) * 136 + kt * 32 + fk];
        s0 = __builtin_amdgcn_mfma_f32_16x16x32_bf16(af, b0, s0, 0, 0, 0);
        s1 = __builtin_amdgcn_mfma_f32_16x16x32_bf16(af, b1, s1, 0, 0, 0);
    }

    // ---- per-row / per-col RMSNorm scalars (lane's col == frow == its B-row)
    const float ksc0 = rsqrtf(sumsq[(size_t)(bb + kr0) * 2 + 1] * (1.0f / DIM) + RMS_EPS);
    const float ksc1 = rsqrtf(sumsq[(size_t)(r0 + w * 16 + frow) * 2 + 1] * (1.0f / DIM) + RMS_EPS);
    float qs[4];
    #pragma unroll
    for (int r = 0; r < 4; ++r)
        qs[r] = rsqrtf(sumsq[(size_t)(r0 + w * 16 + quad * 4 + r) * 2] * (1.0f / DIM) + RMS_EPS);

    // ---- bias + mask + softmax (C-layout: rows m=quad*4+r, col=frow)
    const float scl   = 0.088388347648318447f;   // 1/sqrt(128)
    const float slope = exp2f(-(float)(h + 1));
    const bool  lead  = (i0 == 0) && (w == 0);
    const int   col   = frow;
    float inv[4];
    #pragma unroll
    for (int r = 0; r < 4; ++r) {
        const int m = quad * 4 + r;
        const float sc0 = scl * qs[r] * ksc0;
        const float sc1 = scl * qs[r] * ksc1;
        float v0 = (col < m || lead) ? -1e30f : s0[r] * sc0 + slope * (float)(col - 16 - m);
        float v1 = (col > m)         ? -1e30f : s1[r] * sc1 + slope * (float)(col - m);
        float mx = fmaxf(v0, v1);
        #pragma unroll
        for (int off = 1; off < 16; off <<= 1) mx = fmaxf(mx, __shfl_xor(mx, off, 64));
        const float e0 = __expf(v0 - mx);
        const float e1 = __expf(v1 - mx);
        float sm = e0 + e1;
        #pragma unroll
        for (int off = 1; off < 16; off <<= 1) sm += __shfl_xor(sm, off, 64);
        inv[r] = 1.0f / sm;
        Plds[(w * 16 + m) * 40 + col]      = f2b(e0);
        Plds[(w * 16 + m) * 40 + 16 + col] = f2b(e1);
    }

    // ---- O = P V (Plds: wave-local 16-row stripe -> no block sync needed)
    const bf16x8 pf = *(const bf16x8*)&Plds[(w * 16 + frow) * 40 + fk];
    f32x4 oa[8];
    #pragma unroll
    for (int nt = 0; nt < 8; ++nt) {
        oa[nt][0] = 0.f; oa[nt][1] = 0.f; oa[nt][2] = 0.f; oa[nt][3] = 0.f;
        const bf16x8 vf = *(const bf16x8*)&Vt[(nt * 16 + frow) * 88 + w * 16 + fk];
        oa[nt] = __builtin_amdgcn_mfma_f32_16x16x32_bf16(pf, vf, oa[nt], 0, 0, 0);
    }

    #pragma unroll
    for (int nt = 0; nt < 8; ++nt)
        #pragma unroll
        for (int r = 0; r < 4; ++r) {
            const int m = quad * 4 + r;
            o[(size_t)(r0 + w * 16 + m) * DIM + h * HDIM + nt * 16 + col] =
                f2b(oa[nt][r] * inv[r]);
        }
}

// ---------------- launch ----------------
extern "C" void kernel_launch(void* const* d_in, const int* in_sizes, int n_in,
                              void* d_out, int out_size, void* d_ws, size_t ws_size,
                              hipStream_t stream)
{
    const float* x  = (const float*)d_in[0];
    const float* wq = (const float*)d_in[1];
    const float* wk = (const float*)d_in[2];
    const float* wv = (const float*)d_in[3];
    const float* wo = (const float*)d_in[4];
    const float* qw = (const float*)d_in[5];
    const float* kw = (const float*)d_in[6];
    float* out = (float*)d_out;

    // ws: xb 16MB | weights 8MB | qkv planes 48MB | ob 16MB | sumsq 64KB  (~88MB)
    unsigned short* xb   = (unsigned short*)d_ws;
    unsigned short* wb   = xb + (size_t)MROWS * DIM;              // wq|wk|wv|wo
    unsigned short* qkvp = wb + (size_t)4 * DIM * DIM;            // 24 head-planes
    unsigned short* ob   = qkvp + (size_t)MROWS * QKVDIM;
    float*          ssq  = (float*)(ob + (size_t)MROWS * DIM);
    unsigned short* wob  = wb + (size_t)3 * DIM * DIM;

    cast_all<<<12304, 256, 0, stream>>>(x, wq, wk, wv, wo, xb, wb, ssq);

    // merged QKV: 24x64 = 1536 blocks at 5 blocks/CU (1280 co-resident)
    gemm_nt_128<unsigned short, true><<<dim3(QKVDIM / 128, MROWS / 128), 256, 0, stream>>>(
        xb, wb, qkvp, ssq, MROWS, QKVDIM, DIM);

    attn_mfma<<<dim3(MROWS / 64, NHEADS), 256, 0, stream>>>(qkvp, ssq, qw, kw, ob);

    // O-projection: 8x64 = 512 blocks (fully resident)
    gemm_nt_128<float, false><<<dim3(DIM / 128, MROWS / 128), 256, 0, stream>>>(
        ob, wob, out, nullptr, MROWS, DIM, DIM);
}

// Round 12
// 197.437 us; speedup vs baseline: 2.2066x; 2.2066x over previous
//
#include <hip/hip_runtime.h>
#include <math.h>

// Problem constants (fixed by the reference)
#define NHEADS 8
#define HDIM   128
#define WIN    16
#define DIM    1024
#define QKVDIM 3072
#define SEQ    2048
#define BATCH  4
#define MROWS  (BATCH * SEQ)   // 8192
#define RMS_EPS 1e-6f
#define PLANE  ((size_t)MROWS * HDIM)   // one head-plane of q/k/v (8192 x 128)

typedef __bf16 bf16x8 __attribute__((ext_vector_type(8)));
typedef unsigned short u16x8 __attribute__((ext_vector_type(8)));
typedef float  f32x4  __attribute__((ext_vector_type(4)));

// ---------------- bf16 bit helpers (RNE) ----------------
__device__ __forceinline__ unsigned short f2b(float f) {
    union { float f; unsigned u; } c; c.f = f;
    return (unsigned short)((c.u + 0x7FFFu + ((c.u >> 16) & 1u)) >> 16);
}
__device__ __forceinline__ float b2f(unsigned short u) {
    union { unsigned u; float f; } c; c.u = ((unsigned)u) << 16; return c.f;
}
__device__ __forceinline__ bf16x8 u2b(u16x8 u) {
    union { u16x8 u; bf16x8 b; } c; c.u = u; return c.b;
}

// ---------------- fused cast: x + 4 weights + zero sumsq ----------------
__global__ __launch_bounds__(256) void cast_all(const float* __restrict__ x,
                                                const float* __restrict__ w0,
                                                const float* __restrict__ w1,
                                                const float* __restrict__ w2,
                                                const float* __restrict__ w3,
                                                unsigned short* __restrict__ xb,
                                                unsigned short* __restrict__ wb,
                                                float* __restrict__ sumsq)
{
    const int b = blockIdx.x;
    const int t = threadIdx.x;
    if (b >= 12288) {   // zero the 8192x2 f32 sumsq buffer (ws is poisoned 0xAA)
        ((float4*)sumsq)[(b - 12288) * 256 + t] = make_float4(0.f, 0.f, 0.f, 0.f);
        return;
    }
    const float* src;
    unsigned short* dst;
    int i;
    if (b < 8192) {
        i = b * 256 + t;
        src = x; dst = xb;
    } else {
        const int bb = b - 8192;
        const int which = bb >> 10;
        i = (bb & 1023) * 256 + t;
        src = which == 0 ? w0 : which == 1 ? w1 : which == 2 ? w2 : w3;
        dst = wb + (size_t)which * DIM * DIM;
    }
    const float4 v = ((const float4*)src)[i];
    ushort4 o;
    o.x = f2b(v.x); o.y = f2b(v.y); o.z = f2b(v.z); o.w = f2b(v.w);
    ((ushort4*)dst)[i] = o;
}

// ---------------- 128x128 4-wave MFMA GEMM (NT), m97 structure: single-buffer + max TLP ----------------
// BM=BN=128 BK=64, 256 threads = 4 waves (2M x 2N), per-wave 64x64 (acc[4][4]).
// SINGLE-buffered LDS (32 KiB) -> up to 5 blocks/CU (20 waves/CU). Per-block
// barrier drain is masked by the OTHER resident blocks' waves (m97/m114).
// r11 LESSON: __launch_bounds__(256,5) set the VGPR budget to ~102 -> compiler
// allocated 48 VGPR and SPILLED the 64-VGPR accumulator to scratch (WRITE_SIZE
// 57 MB -> 597 MB, MfmaUtil 7.8%). Second arg is waves PER SIMD: use 4 ->
// budget 128 >= the kernel's natural 88, no spill; runtime occupancy still 5
// blocks/CU (LDS 160/32=5, VGPR 512/88=5).
// Per K-tile: __syncthreads; stage A(4)+B(4); __syncthreads; frag reads + 32 MFMA.
#define LDA8() { \
    _Pragma("unroll") for (int il = 0; il < 4; ++il) { \
        const int rr = (wm * 64 + il * 16 + frow) * 64; \
        af[il][0] = *(const bf16x8*)&As[rr + cs0]; \
        af[il][1] = *(const bf16x8*)&As[rr + cs1]; \
    } }

#define LDB4(bh, bgr) { \
    _Pragma("unroll") for (int jl = 0; jl < 2; ++jl) { \
        const int rr = (wn * 64 + (bh) * 32 + jl * 16 + frow) * 64; \
        bgr[jl][0] = *(const bf16x8*)&Bs[rr + cs0]; \
        bgr[jl][1] = *(const bf16x8*)&Bs[rr + cs1]; \
    } }

#define MMA16(bh, bgr) { \
    _Pragma("unroll") for (int il = 0; il < 4; ++il) \
    _Pragma("unroll") for (int jl = 0; jl < 2; ++jl) { \
        acc[il][(bh)*2+jl] = __builtin_amdgcn_mfma_f32_16x16x32_bf16(af[il][0], bgr[jl][0], acc[il][(bh)*2+jl], 0, 0, 0); \
        acc[il][(bh)*2+jl] = __builtin_amdgcn_mfma_f32_16x16x32_bf16(af[il][1], bgr[jl][1], acc[il][(bh)*2+jl], 0, 0, 0); \
    } }

// 128 rows / (4 waves x 8 rows per instr) = 4 gload_lds per thread per matrix.
#define STAGE_A(kt) { \
    _Pragma("unroll") for (int s2 = 0; s2 < 4; ++s2) { \
        const int rb = s2 * 32; \
        __builtin_amdgcn_global_load_lds( \
            (const __attribute__((address_space(1))) void*)(gA + (size_t)rb * K + (kt)), \
            (__attribute__((address_space(3))) void*)&As[(rb + wid * 8) * 64], 16, 0, 0); \
    } }

#define STAGE_B(kt) { \
    _Pragma("unroll") for (int s2 = 0; s2 < 4; ++s2) { \
        const int rb = s2 * 32; \
        __builtin_amdgcn_global_load_lds( \
            (const __attribute__((address_space(1))) void*)(gB + (size_t)rb * K + (kt)), \
            (__attribute__((address_space(3))) void*)&Bs[(rb + wid * 8) * 64], 16, 0, 0); \
    } }

template <typename TC, bool PLANAR>
__global__ __launch_bounds__(256, 4) void gemm_nt_128(const unsigned short* __restrict__ A,
                                                      const unsigned short* __restrict__ B,
                                                      TC* __restrict__ C,
                                                      float* __restrict__ sumsq,
                                                      int M, int N, int K)
{
    __shared__ __align__(16) __bf16 As[128 * 64];
    __shared__ __align__(16) __bf16 Bs[128 * 64];

    const int t    = threadIdx.x;
    const int wid  = t >> 6;
    const int lane = t & 63;
    const int wm   = wid >> 1;          // 0..1  (64-row band)
    const int wn   = wid & 1;           // 0..1  (64-col band)
    const int bm0  = blockIdx.y * 128;
    const int bn0  = blockIdx.x * 128;

    const int frow = lane & 15;
    const int quad = lane >> 4;
    const int cs0  = ((quad    ) ^ (frow & 7)) * 8;
    const int cs1  = ((quad + 4) ^ (frow & 7)) * 8;

    const int lr = lane >> 3;
    const int lc = (lane & 7) ^ lr;
    const unsigned short* gA = A + (size_t)(bm0 + wid * 8 + lr) * K + lc * 8;
    const unsigned short* gB = B + (size_t)(bn0 + wid * 8 + lr) * K + lc * 8;

    f32x4 acc[4][4];
    #pragma unroll
    for (int i = 0; i < 4; ++i)
        #pragma unroll
        for (int j = 0; j < 4; ++j)
            #pragma unroll
            for (int e = 0; e < 4; ++e) acc[i][j][e] = 0.f;

    bf16x8 af[4][2], bg0[2][2], bg1[2][2];

    for (int kt = 0; kt < K; kt += 64) {
        __syncthreads();                 // previous tile's ds_reads retired
        STAGE_A(kt); STAGE_B(kt);        // 8 global_load_lds
        __syncthreads();                 // compiler drains vmcnt(0) before barrier;
                                         // the stall is masked by other resident blocks
        LDA8(); LDB4(0, bg0); LDB4(1, bg1);
        MMA16(0, bg0); MMA16(1, bg1);
    }

    // ---- epilogue: C/D layout col=lane&15, row=(lane>>4)*4+reg
    const int m_base = bm0 + wm * 64;
    const int n_base = bn0 + wn * 64;
    if constexpr (PLANAR) {
        // col n -> plane n>>7 (q heads 0-7 | k 8-15 | v 16-23), offset n&127
        size_t cb[4];
        #pragma unroll
        for (int j = 0; j < 4; ++j) {
            const int nb = n_base + j * 16;
            cb[j] = (size_t)(nb >> 7) * PLANE + (nb & 127);
        }
        #pragma unroll
        for (int il = 0; il < 4; ++il)
            #pragma unroll
            for (int r = 0; r < 4; ++r) {
                const size_t row = m_base + il * 16 + quad * 4 + r;
                #pragma unroll
                for (int j = 0; j < 4; ++j)
                    ((unsigned short*)C)[cb[j] + row * HDIM + frow] = f2b(acc[il][j][r]);
            }
        if (sumsq != nullptr && bn0 < 2 * DIM) {
            const int which = bn0 >> 10;   // 0 = q cols, 1 = k cols
            #pragma unroll
            for (int il = 0; il < 4; ++il)
                #pragma unroll
                for (int r = 0; r < 4; ++r) {
                    float p = acc[il][0][r] * acc[il][0][r] + acc[il][1][r] * acc[il][1][r]
                            + acc[il][2][r] * acc[il][2][r] + acc[il][3][r] * acc[il][3][r];
                    p += __shfl_xor(p, 1, 64);
                    p += __shfl_xor(p, 2, 64);
                    p += __shfl_xor(p, 4, 64);
                    p += __shfl_xor(p, 8, 64);
                    if (frow == 0)
                        atomicAdd(&sumsq[(size_t)(m_base + il * 16 + quad * 4 + r) * 2 + which], p);
                }
        }
    } else {
        #pragma unroll
        for (int il = 0; il < 4; ++il)
            #pragma unroll
            for (int r = 0; r < 4; ++r) {
                TC* crow = C + (size_t)(m_base + il * 16 + quad * 4 + r) * N + n_base + frow;
                #pragma unroll
                for (int j = 0; j < 4; ++j)
                    crow[j * 16] = acc[il][j][r];
            }
    }
}

// ---------------- MFMA sliding-window attention (head-planar, K LDS-staged) ----------------
// BYTE-IDENTICAL to rounds 9/10 (best measured attn: qw*kw folded into K
// staging, Q prefetched to regs, per-row rsqrt post-MFMA).
__global__ __launch_bounds__(256) void attn_mfma(const unsigned short* __restrict__ qkvp,
                                                 const float* __restrict__ sumsq,
                                                 const float* __restrict__ qw,
                                                 const float* __restrict__ kw,
                                                 unsigned short* __restrict__ o)
{
    __shared__ __align__(16) unsigned short Klds[80 * 136];
    __shared__ __align__(16) unsigned short Vt[128 * 88];
    __shared__ __align__(16) unsigned short Plds[4 * 16 * 40];

    const int t  = threadIdx.x;
    const int qb = blockIdx.x;
    const int h  = blockIdx.y;
    const int r0 = qb * 64;             // first query's global row
    const int i0 = r0 & (SEQ - 1);      // seq-local (block never spans batches)
    const int bb = r0 - i0;             // batch base row

    const unsigned short* qg = qkvp + (size_t)h * PLANE;
    const unsigned short* kg = qkvp + (size_t)(NHEADS + h) * PLANE;
    const unsigned short* vg = qkvp + (size_t)(2 * NHEADS + h) * PLANE;

    const int w    = t >> 6;
    const int lane = t & 63;
    const int frow = lane & 15;
    const int quad = lane >> 4;
    const int fk   = quad * 8;

    // ---- Q prefetch (raw; latency hidden under staging below)
    const size_t qrow = (size_t)(r0 + w * 16 + frow) * HDIM;
    u16x8 qa[4];
    #pragma unroll
    for (int kt = 0; kt < 4; ++kt)
        qa[kt] = *(const u16x8*)(qg + qrow + kt * 32 + fk);

    // ---- stage K (qw*kw fused) and V (transposed)
    #pragma unroll
    for (int it = 0; it < 5; ++it) {
        const int c = it * 256 + t;
        {   // K rows i0-16 .. i0+63  ->  Klds[0..79][.], scaled by qw*kw per channel
            const int lr2 = c >> 4, c8 = c & 15;
            const int ks = i0 - 16 + lr2;
            const int rc = ks < 0 ? 0 : ks;      // clamped rows masked later
            const u16x8 kv = *(const u16x8*)(kg + (size_t)(bb + rc) * HDIM + c8 * 8);
            u16x8 ko;
            #pragma unroll
            for (int e = 0; e < 8; ++e) {
                const int d = h * HDIM + c8 * 8 + e;
                ko[e] = f2b(b2f(kv[e]) * qw[d] * kw[d]);
            }
            *(u16x8*)&Klds[lr2 * 136 + c8 * 8] = ko;
        }
        {   // V transposed scatter
            const int c8 = c / 80, lr2 = c - c8 * 80;
            const int ks = i0 - 16 + lr2;
            const int rc = ks < 0 ? 0 : ks;      // clamped rows get P == 0
            const u16x8 vv = *(const u16x8*)(vg + (size_t)(bb + rc) * HDIM + c8 * 8);
            #pragma unroll
            for (int e = 0; e < 8; ++e)
                Vt[(c8 * 8 + e) * 88 + lr2] = vv[e];
        }
    }
    __syncthreads();

    // ---- S = Q K^T (Q raw from regs; channel weights already in K)
    const int kidx0 = i0 - 16 + w * 16 + frow;             // s0 key (seq-local)
    const int kr0   = kidx0 < 0 ? 0 : kidx0;               // clamped; masked below

    f32x4 s0 = {0.f, 0.f, 0.f, 0.f}, s1 = {0.f, 0.f, 0.f, 0.f};
    #pragma unroll
    for (int kt = 0; kt < 4; ++kt) {
        const bf16x8 af = u2b(qa[kt]);
        const bf16x8 b0 = *(const bf16x8*)&Klds[(w * 16 + frow) * 136 + kt * 32 + fk];
        const bf16x8 b1 = *(const bf16x8*)&Klds[(w * 16 + 16 + frow) * 136 + kt * 32 + fk];
        s0 = __builtin_amdgcn_mfma_f32_16x16x32_bf16(af, b0, s0, 0, 0, 0);
        s1 = __builtin_amdgcn_mfma_f32_16x16x32_bf16(af, b1, s1, 0, 0, 0);
    }

    // ---- per-row / per-col RMSNorm scalars (lane's col == frow == its B-row)
    const float ksc0 = rsqrtf(sumsq[(size_t)(bb + kr0) * 2 + 1] * (1.0f / DIM) + RMS_EPS);
    const float ksc1 = rsqrtf(sumsq[(size_t)(r0 + w * 16 + frow) * 2 + 1] * (1.0f / DIM) + RMS_EPS);
    float qs[4];
    #pragma unroll
    for (int r = 0; r < 4; ++r)
        qs[r] = rsqrtf(sumsq[(size_t)(r0 + w * 16 + quad * 4 + r) * 2] * (1.0f / DIM) + RMS_EPS);

    // ---- bias + mask + softmax (C-layout: rows m=quad*4+r, col=frow)
    const float scl   = 0.088388347648318447f;   // 1/sqrt(128)
    const float slope = exp2f(-(float)(h + 1));
    const bool  lead  = (i0 == 0) && (w == 0);
    const int   col   = frow;
    float inv[4];
    #pragma unroll
    for (int r = 0; r < 4; ++r) {
        const int m = quad * 4 + r;
        const float sc0 = scl * qs[r] * ksc0;
        const float sc1 = scl * qs[r] * ksc1;
        float v0 = (col < m || lead) ? -1e30f : s0[r] * sc0 + slope * (float)(col - 16 - m);
        float v1 = (col > m)         ? -1e30f : s1[r] * sc1 + slope * (float)(col - m);
        float mx = fmaxf(v0, v1);
        #pragma unroll
        for (int off = 1; off < 16; off <<= 1) mx = fmaxf(mx, __shfl_xor(mx, off, 64));
        const float e0 = __expf(v0 - mx);
        const float e1 = __expf(v1 - mx);
        float sm = e0 + e1;
        #pragma unroll
        for (int off = 1; off < 16; off <<= 1) sm += __shfl_xor(sm, off, 64);
        inv[r] = 1.0f / sm;
        Plds[(w * 16 + m) * 40 + col]      = f2b(e0);
        Plds[(w * 16 + m) * 40 + 16 + col] = f2b(e1);
    }

    // ---- O = P V (Plds: wave-local 16-row stripe -> no block sync needed)
    const bf16x8 pf = *(const bf16x8*)&Plds[(w * 16 + frow) * 40 + fk];
    f32x4 oa[8];
    #pragma unroll
    for (int nt = 0; nt < 8; ++nt) {
        oa[nt][0] = 0.f; oa[nt][1] = 0.f; oa[nt][2] = 0.f; oa[nt][3] = 0.f;
        const bf16x8 vf = *(const bf16x8*)&Vt[(nt * 16 + frow) * 88 + w * 16 + fk];
        oa[nt] = __builtin_amdgcn_mfma_f32_16x16x32_bf16(pf, vf, oa[nt], 0, 0, 0);
    }

    #pragma unroll
    for (int nt = 0; nt < 8; ++nt)
        #pragma unroll
        for (int r = 0; r < 4; ++r) {
            const int m = quad * 4 + r;
            o[(size_t)(r0 + w * 16 + m) * DIM + h * HDIM + nt * 16 + col] =
                f2b(oa[nt][r] * inv[r]);
        }
}

// ---------------- launch ----------------
extern "C" void kernel_launch(void* const* d_in, const int* in_sizes, int n_in,
                              void* d_out, int out_size, void* d_ws, size_t ws_size,
                              hipStream_t stream)
{
    const float* x  = (const float*)d_in[0];
    const float* wq = (const float*)d_in[1];
    const float* wk = (const float*)d_in[2];
    const float* wv = (const float*)d_in[3];
    const float* wo = (const float*)d_in[4];
    const float* qw = (const float*)d_in[5];
    const float* kw = (const float*)d_in[6];
    float* out = (float*)d_out;

    // ws: xb 16MB | weights 8MB | qkv planes 48MB | ob 16MB | sumsq 64KB  (~88MB)
    unsigned short* xb   = (unsigned short*)d_ws;
    unsigned short* wb   = xb + (size_t)MROWS * DIM;              // wq|wk|wv|wo
    unsigned short* qkvp = wb + (size_t)4 * DIM * DIM;            // 24 head-planes
    unsigned short* ob   = qkvp + (size_t)MROWS * QKVDIM;
    float*          ssq  = (float*)(ob + (size_t)MROWS * DIM);
    unsigned short* wob  = wb + (size_t)3 * DIM * DIM;

    cast_all<<<12304, 256, 0, stream>>>(x, wq, wk, wv, wo, xb, wb, ssq);

    // merged QKV: 24x64 = 1536 blocks at up to 5 blocks/CU
    gemm_nt_128<unsigned short, true><<<dim3(QKVDIM / 128, MROWS / 128), 256, 0, stream>>>(
        xb, wb, qkvp, ssq, MROWS, QKVDIM, DIM);

    attn_mfma<<<dim3(MROWS / 64, NHEADS), 256, 0, stream>>>(qkvp, ssq, qw, kw, ob);

    // O-projection: 8x64 = 512 blocks
    gemm_nt_128<float, false><<<dim3(DIM / 128, MROWS / 128), 256, 0, stream>>>(
        ob, wob, out, nullptr, MROWS, DIM, DIM);
}